// Round 3
// baseline (299.559 us; speedup 1.0000x reference)
//
#include <hip/hip_runtime.h>
#include <hip/hip_bf16.h>

#define TTLEN 2048
#define NCH   64
#define CLEN  32    // TTLEN / NCH

typedef unsigned short ushort_t;
typedef __attribute__((ext_vector_type(8))) short short8;
typedef __attribute__((ext_vector_type(4))) float f32x4;

__device__ __forceinline__ unsigned short f2bf(float f) {
    __hip_bfloat16 h = __float2bfloat16(f);
    return *reinterpret_cast<unsigned short*>(&h);
}
__device__ __forceinline__ float bf2f(unsigned int u16) {
    union { unsigned int i; float f; } v; v.i = u16 << 16; return v.f;
}

// ---------------- weights fp32 -> bf16, all four in one launch ----------------
__global__ void convert4(const float* __restrict__ Wk, const float* __restrict__ Wv,
                         const float* __restrict__ Wr, const float* __restrict__ Wo,
                         ushort_t* __restrict__ Wall, ushort_t* __restrict__ Wob) {
    int m = blockIdx.x >> 8;                       // 0..3
    const float* src = (m == 0) ? Wk : (m == 1) ? Wv : (m == 2) ? Wr : Wo;
    ushort_t* dst = (m == 3) ? Wob : Wall + (size_t)m * 262144;
    int i = (blockIdx.x & 255) * 256 + threadIdx.x;  // group of 4
    float4 v = *(const float4*)(src + (size_t)i * 4);
    union { unsigned short u[4]; uint2 p; } pk;
    pk.u[0] = f2bf(v.x); pk.u[1] = f2bf(v.y); pk.u[2] = f2bf(v.z); pk.u[3] = f2bf(v.w);
    *(uint2*)(dst + (size_t)i * 4) = pk.p;
}

// ------------- time-shift mix: one x read, three bf16 outputs -------------
__global__ void mix3(const float* __restrict__ x,
                     const float* __restrict__ tmk, const float* __restrict__ tmv,
                     const float* __restrict__ tmr,
                     ushort_t* __restrict__ xk, ushort_t* __restrict__ xv,
                     ushort_t* __restrict__ xr) {
    int i   = blockIdx.x * 256 + threadIdx.x;      // group of 4 channels
    int c4  = (i & 127) << 2;
    int row = i >> 7;                              // b*T + t
    int t   = row & (TTLEN - 1);
    float4 xc = *(const float4*)(x + (size_t)row * 512 + c4);
    float4 xp = make_float4(0.f, 0.f, 0.f, 0.f);
    if (t != 0) xp = *(const float4*)(x + (size_t)(row - 1) * 512 + c4);
    size_t o = (size_t)row * 512 + c4;
    union { unsigned short u[4]; uint2 p; } pk;
    {
        float4 tv = *(const float4*)(tmk + c4);
        pk.u[0] = f2bf(xc.x * tv.x + xp.x * (1.f - tv.x));
        pk.u[1] = f2bf(xc.y * tv.y + xp.y * (1.f - tv.y));
        pk.u[2] = f2bf(xc.z * tv.z + xp.z * (1.f - tv.z));
        pk.u[3] = f2bf(xc.w * tv.w + xp.w * (1.f - tv.w));
        *(uint2*)(xk + o) = pk.p;
    }
    {
        float4 tv = *(const float4*)(tmv + c4);
        pk.u[0] = f2bf(xc.x * tv.x + xp.x * (1.f - tv.x));
        pk.u[1] = f2bf(xc.y * tv.y + xp.y * (1.f - tv.y));
        pk.u[2] = f2bf(xc.z * tv.z + xp.z * (1.f - tv.z));
        pk.u[3] = f2bf(xc.w * tv.w + xp.w * (1.f - tv.w));
        *(uint2*)(xv + o) = pk.p;
    }
    {
        float4 tv = *(const float4*)(tmr + c4);
        pk.u[0] = f2bf(xc.x * tv.x + xp.x * (1.f - tv.x));
        pk.u[1] = f2bf(xc.y * tv.y + xp.y * (1.f - tv.y));
        pk.u[2] = f2bf(xc.z * tv.z + xp.z * (1.f - tv.z));
        pk.u[3] = f2bf(xc.w * tv.w + xp.w * (1.f - tv.w));
        *(uint2*)(xr + o) = pk.p;
    }
}

// ---- register-fragment GEMM: no LDS, no barriers, double-buffered prefetch ----
// A fragment for lane l, tile mt, stage st, half s:
//   A[mBlk+wm+mt*16+(l&15)][st*64 + s*32 + (l>>4)*8 .. +8]  -> 16B contiguous load
// MODE 0: fused k/v/r (N=1536, A per 512-col band, bf16 out, epilogue per band)
// MODE 1: out-projection (N=512, fp32 out, *gamma[t])
template <int MODE>
__launch_bounds__(256, 2)
__global__ void gemm_reg(const ushort_t* __restrict__ Axk, const ushort_t* __restrict__ Axv,
                         const ushort_t* __restrict__ Axr, const ushort_t* __restrict__ W,
                         const float* __restrict__ b0, const float* __restrict__ b1,
                         const float* __restrict__ b2,
                         ushort_t* __restrict__ o0, ushort_t* __restrict__ o1,
                         ushort_t* __restrict__ o2,
                         float* __restrict__ fout, const float* __restrict__ gamma) {
    const int tid  = threadIdx.x;
    const int lane = tid & 63;
    const int w    = tid >> 6;
    const int wm   = (w >> 1) << 6;
    const int wn   = (w & 1) << 6;
    const int mBlk = blockIdx.y << 7;
    const int nBlk = blockIdx.x << 7;
    const int r16  = lane & 15, q = lane >> 4;

    const int p = nBlk >> 9;   // projection band (MODE 0)
    const ushort_t* A = (MODE == 1) ? Axk : (p == 0 ? Axk : (p == 1 ? Axv : Axr));

    // lane base pointers (mt stride = 16 rows * 512 = 8192 elems)
    const ushort_t* Ab = A + (size_t)(mBlk + wm + r16) * 512 + q * 8;
    const ushort_t* Bb = W + (size_t)(nBlk + wn + r16) * 512 + q * 8;

    f32x4 acc[4][4];
#pragma unroll
    for (int a = 0; a < 4; ++a)
#pragma unroll
        for (int b = 0; b < 4; ++b) acc[a][b] = (f32x4){0.f, 0.f, 0.f, 0.f};

    short8 aB[2][2][4], bB[2][2][4];   // [buf][s][tile]
#pragma unroll
    for (int s = 0; s < 2; ++s)
#pragma unroll
        for (int t = 0; t < 4; ++t) {
            aB[0][s][t] = *(const short8*)(Ab + t * 8192 + s * 32);
            bB[0][s][t] = *(const short8*)(Bb + t * 8192 + s * 32);
        }

#pragma unroll 2
    for (int st = 0; st < 8; ++st) {
        const int cur = st & 1, nxt = cur ^ 1;
        if (st < 7) {
            const int kn = (st + 1) * 64;
#pragma unroll
            for (int s = 0; s < 2; ++s)
#pragma unroll
                for (int t = 0; t < 4; ++t) {
                    aB[nxt][s][t] = *(const short8*)(Ab + kn + t * 8192 + s * 32);
                    bB[nxt][s][t] = *(const short8*)(Bb + kn + t * 8192 + s * 32);
                }
        }
#pragma unroll
        for (int s = 0; s < 2; ++s)
#pragma unroll
            for (int mt = 0; mt < 4; ++mt)
#pragma unroll
                for (int nt = 0; nt < 4; ++nt)
                    acc[mt][nt] = __builtin_amdgcn_mfma_f32_16x16x32_bf16(
                        aB[cur][s][mt], bB[cur][s][nt], acc[mt][nt], 0, 0, 0);
    }

    if (MODE == 0) {
        const float* bias = (p == 0) ? b0 : (p == 1) ? b1 : b2;
        ushort_t* outp = (p == 0) ? o0 : (p == 1) ? o1 : o2;
#pragma unroll
        for (int mt = 0; mt < 4; ++mt) {
#pragma unroll
            for (int nt = 0; nt < 4; ++nt) {
                int nLocal = (nBlk & 511) + wn + nt * 16 + r16;
                float bv = bias[nLocal];
#pragma unroll
                for (int i = 0; i < 4; ++i) {
                    int row = mBlk + wm + mt * 16 + (q << 2) + i;
                    float v = acc[mt][nt][i] + bv;
                    if (p == 0) v = __expf(fminf(fmaxf(v, -60.f), 30.f));
                    else if (p == 2) v = 1.f / (1.f + __expf(-v));
                    outp[(size_t)row * 512 + nLocal] = f2bf(v);
                }
            }
        }
    } else {
#pragma unroll
        for (int mt = 0; mt < 4; ++mt) {
#pragma unroll
            for (int nt = 0; nt < 4; ++nt) {
                int col = nBlk + wn + nt * 16 + r16;
                float bv = b0[col];
#pragma unroll
                for (int i = 0; i < 4; ++i) {
                    int row = mBlk + wm + mt * 16 + (q << 2) + i;
                    float v = (acc[mt][nt][i] + bv) * gamma[row & (TTLEN - 1)];
                    fout[(size_t)row * 512 + col] = v;
                }
            }
        }
    }
}

// ---------------- scan phase A: per-chunk local (S, sum_k), bf16 in, 4 ch/thread ----
__global__ void scanA(const ushort_t* __restrict__ kb, const ushort_t* __restrict__ vb,
                      const float* __restrict__ tw, const float* __restrict__ alpha,
                      float* __restrict__ Sloc, float* __restrict__ Kloc) {
    int b = blockIdx.x >> 6, j = blockIdx.x & 63;
    int a0 = threadIdx.x * 4;                      // 128 threads x 4 channels
    int h = a0 >> 6;
    float r = tw[h * TTLEN + TTLEN - 2];
    int t0 = j * CLEN;
    size_t base = ((size_t)(b * TTLEN + t0)) * 512 + a0;
    const float* al = alpha + h * TTLEN + t0;
    float s[4] = {0.f, 0.f, 0.f, 0.f}, sk[4] = {0.f, 0.f, 0.f, 0.f};
#pragma unroll 8
    for (int it = 0; it < CLEN; ++it) {
        uint2 kk = *(const uint2*)(kb + base + (size_t)it * 512);
        uint2 vv = *(const uint2*)(vb + base + (size_t)it * 512);
        float kf[4] = {bf2f(kk.x & 0xffff), bf2f(kk.x >> 16),
                       bf2f(kk.y & 0xffff), bf2f(kk.y >> 16)};
        float vf[4] = {bf2f(vv.x & 0xffff), bf2f(vv.x >> 16),
                       bf2f(vv.y & 0xffff), bf2f(vv.y >> 16)};
        float av = al[it];
#pragma unroll
        for (int c = 0; c < 4; ++c) {
            sk[c] += kf[c];
            s[c] = fmaf(r, s[c], av * kf[c] * vf[c]);
        }
    }
    int o = (b * NCH + j) * 512 + a0;
    *(float4*)(Sloc + o) = make_float4(s[0], s[1], s[2], s[3]);
    *(float4*)(Kloc + o) = make_float4(sk[0], sk[1], sk[2], sk[3]);
}

// ---------------- scan mid: exclusive prefix across chunks ----------------
__global__ void scanMid(const float* __restrict__ tw,
                        const float* __restrict__ Sloc, const float* __restrict__ Kloc,
                        float* __restrict__ Sin, float* __restrict__ Kin) {
    int idx = blockIdx.x * 256 + threadIdx.x;   // 4096 = B*A
    int a = idx & 511, b = idx >> 9;
    int h = a >> 6;
    float r = tw[h * TTLEN + TTLEN - 2];
    float rL = r;
#pragma unroll
    for (int i = 0; i < 5; ++i) rL *= rL;       // r^32
    float cs = 0.f, ck = 0.f;
#pragma unroll
    for (int j = 0; j < NCH; ++j) {
        int o = (b * NCH + j) * 512 + a;
        Sin[o] = cs; Kin[o] = ck;
        cs = fmaf(rL, cs, Sloc[o]);
        ck += Kloc[o];
    }
}

// ------------- scan phase B: replay with true prefix, emit rwkv bf16, 4 ch/thread ----
__global__ void scanB(const ushort_t* __restrict__ kb, const ushort_t* __restrict__ vb,
                      const ushort_t* __restrict__ rb,
                      const float* __restrict__ tw, const float* __restrict__ alpha,
                      const float* __restrict__ beta,
                      const float* __restrict__ Sin, const float* __restrict__ Kin,
                      ushort_t* __restrict__ rwkv) {
    int b = blockIdx.x >> 6, j = blockIdx.x & 63;
    int a0 = threadIdx.x * 4;
    int h = a0 >> 6;
    float r = tw[h * TTLEN + TTLEN - 2];
    int t0 = j * CLEN;
    size_t base = ((size_t)(b * TTLEN + t0)) * 512 + a0;
    const float* al = alpha + h * TTLEN + t0;
    const float* bt = beta + h * TTLEN + t0;
    int o = (b * NCH + j) * 512 + a0;
    float4 sv = *(const float4*)(Sin + o);
    float4 kv = *(const float4*)(Kin + o);
    float s[4] = {sv.x, sv.y, sv.z, sv.w};
    float sk[4] = {kv.x, kv.y, kv.z, kv.w};
#pragma unroll 4
    for (int it = 0; it < CLEN; ++it) {
        uint2 kk = *(const uint2*)(kb + base + (size_t)it * 512);
        uint2 vv = *(const uint2*)(vb + base + (size_t)it * 512);
        uint2 rr = *(const uint2*)(rb + base + (size_t)it * 512);
        float kf[4] = {bf2f(kk.x & 0xffff), bf2f(kk.x >> 16),
                       bf2f(kk.y & 0xffff), bf2f(kk.y >> 16)};
        float vf[4] = {bf2f(vv.x & 0xffff), bf2f(vv.x >> 16),
                       bf2f(vv.y & 0xffff), bf2f(vv.y >> 16)};
        float rf[4] = {bf2f(rr.x & 0xffff), bf2f(rr.x >> 16),
                       bf2f(rr.y & 0xffff), bf2f(rr.y >> 16)};
        float av = al[it], btv = bt[it];
        unsigned short u[4];
#pragma unroll
        for (int c = 0; c < 4; ++c) {
            sk[c] += kf[c];
            s[c] = fmaf(r, s[c], av * kf[c] * vf[c]);
            u[c] = f2bf(rf[c] * btv * s[c] / sk[c]);
        }
        uint2 outw;
        outw.x = ((unsigned int)u[1] << 16) | u[0];
        outw.y = ((unsigned int)u[3] << 16) | u[2];
        *(uint2*)(rwkv + base + (size_t)it * 512) = outw;
    }
}

extern "C" void kernel_launch(void* const* d_in, const int* in_sizes, int n_in,
                              void* d_out, int out_size, void* d_ws, size_t ws_size,
                              hipStream_t stream) {
    const float* x   = (const float*)d_in[0];
    const float* tw  = (const float*)d_in[1];
    const float* ta  = (const float*)d_in[2];
    const float* tb  = (const float*)d_in[3];
    const float* tg  = (const float*)d_in[4];
    const float* tmk = (const float*)d_in[5];
    const float* tmv = (const float*)d_in[6];
    const float* tmr = (const float*)d_in[7];
    const float* Wk  = (const float*)d_in[8];
    const float* bk  = (const float*)d_in[9];
    const float* Wv  = (const float*)d_in[10];
    const float* bv  = (const float*)d_in[11];
    const float* Wr  = (const float*)d_in[12];
    const float* br  = (const float*)d_in[13];
    const float* Wo  = (const float*)d_in[14];
    const float* bo  = (const float*)d_in[15];

    char* ws = (char*)d_ws;
    ushort_t* Wall = (ushort_t*)(ws + 0);            // [1536][512] bf16 (Wk;Wv;Wr)
    ushort_t* Wob  = (ushort_t*)(ws + 1572864);      // [512][512] bf16
    ushort_t* xk   = (ushort_t*)(ws + 2097152);      // 16.78 MB each
    ushort_t* xv   = (ushort_t*)(ws + 18874368);
    ushort_t* xr   = (ushort_t*)(ws + 35651584);
    ushort_t* kb   = (ushort_t*)(ws + 52428800);
    ushort_t* vb   = (ushort_t*)(ws + 69206016);
    ushort_t* rb   = (ushort_t*)(ws + 85983232);
    ushort_t* rwkv = xk;                             // xk dead after gemm<0>
    float* Sloc = (float*)(ws + 102760448);          // 1 MB each
    float* Kloc = (float*)(ws + 103809024);
    float* Sin  = (float*)(ws + 104857600);
    float* Kin  = (float*)(ws + 105906176);

    convert4<<<1024, 256, 0, stream>>>(Wk, Wv, Wr, Wo, Wall, Wob);
    mix3<<<8192, 256, 0, stream>>>(x, tmk, tmv, tmr, xk, xv, xr);

    gemm_reg<0><<<dim3(12, 128), 256, 0, stream>>>(xk, xv, xr, Wall, bk, bv, br,
                                                   kb, vb, rb, nullptr, nullptr);

    scanA<<<512, 128, 0, stream>>>(kb, vb, tw, ta, Sloc, Kloc);
    scanMid<<<16, 256, 0, stream>>>(tw, Sloc, Kloc, Sin, Kin);
    scanB<<<512, 128, 0, stream>>>(kb, vb, rb, tw, ta, tb, Sin, Kin, rwkv);

    gemm_reg<1><<<dim3(4, 128), 256, 0, stream>>>(rwkv, nullptr, nullptr, Wob, bo, nullptr,
                                                  nullptr, nullptr, nullptr, nullptr,
                                                  (float*)d_out, tg);
}

// Round 4
// 214.425 us; speedup vs baseline: 1.3970x; 1.3970x over previous
//
#include <hip/hip_runtime.h>
#include <hip/hip_bf16.h>

#define TTLEN 2048
#define NCH   64
#define CLEN  32    // TTLEN / NCH

typedef unsigned short ushort_t;
typedef __attribute__((ext_vector_type(8))) short short8;
typedef __attribute__((ext_vector_type(4))) float f32x4;

__device__ __forceinline__ unsigned short f2bf(float f) {
    __hip_bfloat16 h = __float2bfloat16(f);
    return *reinterpret_cast<unsigned short*>(&h);
}
__device__ __forceinline__ float bf2f(unsigned int u16) {
    union { unsigned int i; float f; } v; v.i = u16 << 16; return v.f;
}

#define GLD_LDS16(gp, lp) __builtin_amdgcn_global_load_lds( \
    (const __attribute__((address_space(1))) void*)(gp),    \
    (__attribute__((address_space(3))) void*)(lp), 16, 0, 0)

// ---------------- weights fp32 -> bf16, all four in one launch ----------------
__global__ void convert4(const float* __restrict__ Wk, const float* __restrict__ Wv,
                         const float* __restrict__ Wr, const float* __restrict__ Wo,
                         ushort_t* __restrict__ Wall, ushort_t* __restrict__ Wob) {
    int m = blockIdx.x >> 8;                       // 0..3
    const float* src = (m == 0) ? Wk : (m == 1) ? Wv : (m == 2) ? Wr : Wo;
    ushort_t* dst = (m == 3) ? Wob : Wall + (size_t)m * 262144;
    int i = (blockIdx.x & 255) * 256 + threadIdx.x;  // group of 4
    float4 v = *(const float4*)(src + (size_t)i * 4);
    union { unsigned short u[4]; uint2 p; } pk;
    pk.u[0] = f2bf(v.x); pk.u[1] = f2bf(v.y); pk.u[2] = f2bf(v.z); pk.u[3] = f2bf(v.w);
    *(uint2*)(dst + (size_t)i * 4) = pk.p;
}

// ------------- time-shift mix: one x read, three bf16 outputs -------------
__global__ void mix3(const float* __restrict__ x,
                     const float* __restrict__ tmk, const float* __restrict__ tmv,
                     const float* __restrict__ tmr,
                     ushort_t* __restrict__ xk, ushort_t* __restrict__ xv,
                     ushort_t* __restrict__ xr) {
    int i   = blockIdx.x * 256 + threadIdx.x;      // group of 4 channels
    int c4  = (i & 127) << 2;
    int row = i >> 7;                              // b*T + t
    int t   = row & (TTLEN - 1);
    float4 xc = *(const float4*)(x + (size_t)row * 512 + c4);
    float4 xp = make_float4(0.f, 0.f, 0.f, 0.f);
    if (t != 0) xp = *(const float4*)(x + (size_t)(row - 1) * 512 + c4);
    size_t o = (size_t)row * 512 + c4;
    union { unsigned short u[4]; uint2 p; } pk;
    {
        float4 tv = *(const float4*)(tmk + c4);
        pk.u[0] = f2bf(xc.x * tv.x + xp.x * (1.f - tv.x));
        pk.u[1] = f2bf(xc.y * tv.y + xp.y * (1.f - tv.y));
        pk.u[2] = f2bf(xc.z * tv.z + xp.z * (1.f - tv.z));
        pk.u[3] = f2bf(xc.w * tv.w + xp.w * (1.f - tv.w));
        *(uint2*)(xk + o) = pk.p;
    }
    {
        float4 tv = *(const float4*)(tmv + c4);
        pk.u[0] = f2bf(xc.x * tv.x + xp.x * (1.f - tv.x));
        pk.u[1] = f2bf(xc.y * tv.y + xp.y * (1.f - tv.y));
        pk.u[2] = f2bf(xc.z * tv.z + xp.z * (1.f - tv.z));
        pk.u[3] = f2bf(xc.w * tv.w + xp.w * (1.f - tv.w));
        *(uint2*)(xv + o) = pk.p;
    }
    {
        float4 tv = *(const float4*)(tmr + c4);
        pk.u[0] = f2bf(xc.x * tv.x + xp.x * (1.f - tv.x));
        pk.u[1] = f2bf(xc.y * tv.y + xp.y * (1.f - tv.y));
        pk.u[2] = f2bf(xc.z * tv.z + xp.z * (1.f - tv.z));
        pk.u[3] = f2bf(xc.w * tv.w + xp.w * (1.f - tv.w));
        *(uint2*)(xr + o) = pk.p;
    }
}

// ------- 128x256-tile GEMM, 512 threads (8 waves, 2x4 grid of 64x64 wave-tiles) -------
// BK=64, global_load_lds 16B staging, XOR-swizzled LDS (0 bank conflicts, round-2 verified).
// MODE 0: fused k/v/r (N=1536, A per 512-col band, bf16 out, per-band epilogue), grid(6,128)
// MODE 1: out-projection (N=512, fp32 out, *gamma[t]), grid(2,128)
template <int MODE>
__launch_bounds__(512, 4)
__global__ void gemm_big(const ushort_t* __restrict__ Axk, const ushort_t* __restrict__ Axv,
                         const ushort_t* __restrict__ Axr, const ushort_t* __restrict__ W,
                         const float* __restrict__ b0, const float* __restrict__ b1,
                         const float* __restrict__ b2,
                         ushort_t* __restrict__ o0, ushort_t* __restrict__ o1,
                         ushort_t* __restrict__ o2,
                         float* __restrict__ fout, const float* __restrict__ gamma) {
    __shared__ alignas(16) ushort_t As[128 * 64];   // 16 KB
    __shared__ alignas(16) ushort_t Bs[256 * 64];   // 32 KB
    const int tid  = threadIdx.x;
    const int lane = tid & 63;
    const int w    = tid >> 6;                      // 0..7
    const int wm   = (w >> 2) << 6;                 // 0 or 64
    const int wn   = (w & 3) << 6;                  // 0,64,128,192
    const int mBlk = blockIdx.y << 7;
    const int nBlk = blockIdx.x << 8;
    const int r16  = lane & 15, q = lane >> 4;
    const int rowInW = lane >> 3, ch = lane & 7;

    const int p = (MODE == 0) ? (blockIdx.x >> 1) : 0;   // projection band
    const ushort_t* A = (MODE == 1) ? Axk : (p == 0 ? Axk : (p == 1 ? Axv : Axr));

    f32x4 acc[4][4];
#pragma unroll
    for (int a = 0; a < 4; ++a)
#pragma unroll
        for (int b = 0; b < 4; ++b) acc[a][b] = (f32x4){0.f, 0.f, 0.f, 0.f};

    for (int k0 = 0; k0 < 512; k0 += 64) {
        const ushort_t* Ag = A + (size_t)mBlk * 512 + k0;
        const ushort_t* Bg = W + (size_t)nBlk * 512 + k0;
        // A: 128 rows, wave w stages rows [w*16, w*16+16)
#pragma unroll
        for (int i = 0; i < 2; ++i) {
            int baseRow = w * 16 + i * 8;
            int row = baseRow + rowInW;
            int gch = ch ^ (row & 7);
            GLD_LDS16(Ag + (size_t)row * 512 + gch * 8, &As[baseRow * 64]);
        }
        // B: 256 rows, wave w stages rows [w*32, w*32+32)
#pragma unroll
        for (int i = 0; i < 4; ++i) {
            int baseRow = w * 32 + i * 8;
            int row = baseRow + rowInW;
            int gch = ch ^ (row & 7);
            GLD_LDS16(Bg + (size_t)row * 512 + gch * 8, &Bs[baseRow * 64]);
        }
        asm volatile("s_waitcnt vmcnt(0)" ::: "memory");
        __syncthreads();
#pragma unroll
        for (int s = 0; s < 2; ++s) {
            short8 af[4], bfr[4];
#pragma unroll
            for (int mt = 0; mt < 4; ++mt) {
                int row = wm + mt * 16 + r16;
                af[mt] = *(const short8*)(&As[row * 64 + (((s * 4 + q) ^ (r16 & 7)) << 3)]);
            }
#pragma unroll
            for (int nt = 0; nt < 4; ++nt) {
                int row = wn + nt * 16 + r16;
                bfr[nt] = *(const short8*)(&Bs[row * 64 + (((s * 4 + q) ^ (r16 & 7)) << 3)]);
            }
#pragma unroll
            for (int mt = 0; mt < 4; ++mt)
#pragma unroll
                for (int nt = 0; nt < 4; ++nt)
                    acc[mt][nt] = __builtin_amdgcn_mfma_f32_16x16x32_bf16(
                        af[mt], bfr[nt], acc[mt][nt], 0, 0, 0);
        }
        __syncthreads();
    }

    if (MODE == 0) {
        const float* bias = (p == 0) ? b0 : (p == 1) ? b1 : b2;
        ushort_t* outp = (p == 0) ? o0 : (p == 1) ? o1 : o2;
#pragma unroll
        for (int mt = 0; mt < 4; ++mt) {
#pragma unroll
            for (int nt = 0; nt < 4; ++nt) {
                int nLocal = (nBlk & 511) + wn + nt * 16 + r16;
                float bv = bias[nLocal];
#pragma unroll
                for (int i = 0; i < 4; ++i) {
                    int row = mBlk + wm + mt * 16 + (q << 2) + i;
                    float v = acc[mt][nt][i] + bv;
                    if (p == 0) v = __expf(fminf(fmaxf(v, -60.f), 30.f));
                    else if (p == 2) v = 1.f / (1.f + __expf(-v));
                    outp[(size_t)row * 512 + nLocal] = f2bf(v);
                }
            }
        }
    } else {
#pragma unroll
        for (int mt = 0; mt < 4; ++mt) {
#pragma unroll
            for (int nt = 0; nt < 4; ++nt) {
                int col = nBlk + wn + nt * 16 + r16;
                float bv = b0[col];
#pragma unroll
                for (int i = 0; i < 4; ++i) {
                    int row = mBlk + wm + mt * 16 + (q << 2) + i;
                    float v = (acc[mt][nt][i] + bv) * gamma[row & (TTLEN - 1)];
                    fout[(size_t)row * 512 + col] = v;
                }
            }
        }
    }
}

// ---------------- scan phase A: per-chunk local (S, sum_k), bf16 in, 4 ch/thread ----
__global__ void scanA(const ushort_t* __restrict__ kb, const ushort_t* __restrict__ vb,
                      const float* __restrict__ tw, const float* __restrict__ alpha,
                      float* __restrict__ Sloc, float* __restrict__ Kloc) {
    int b = blockIdx.x >> 6, j = blockIdx.x & 63;
    int a0 = threadIdx.x * 4;                      // 128 threads x 4 channels
    int h = a0 >> 6;
    float r = tw[h * TTLEN + TTLEN - 2];
    int t0 = j * CLEN;
    size_t base = ((size_t)(b * TTLEN + t0)) * 512 + a0;
    const float* al = alpha + h * TTLEN + t0;
    float s[4] = {0.f, 0.f, 0.f, 0.f}, sk[4] = {0.f, 0.f, 0.f, 0.f};
#pragma unroll 8
    for (int it = 0; it < CLEN; ++it) {
        uint2 kk = *(const uint2*)(kb + base + (size_t)it * 512);
        uint2 vv = *(const uint2*)(vb + base + (size_t)it * 512);
        float kf[4] = {bf2f(kk.x & 0xffff), bf2f(kk.x >> 16),
                       bf2f(kk.y & 0xffff), bf2f(kk.y >> 16)};
        float vf[4] = {bf2f(vv.x & 0xffff), bf2f(vv.x >> 16),
                       bf2f(vv.y & 0xffff), bf2f(vv.y >> 16)};
        float av = al[it];
#pragma unroll
        for (int c = 0; c < 4; ++c) {
            sk[c] += kf[c];
            s[c] = fmaf(r, s[c], av * kf[c] * vf[c]);
        }
    }
    int o = (b * NCH + j) * 512 + a0;
    *(float4*)(Sloc + o) = make_float4(s[0], s[1], s[2], s[3]);
    *(float4*)(Kloc + o) = make_float4(sk[0], sk[1], sk[2], sk[3]);
}

// ---------------- scan mid: exclusive prefix across chunks ----------------
__global__ void scanMid(const float* __restrict__ tw,
                        const float* __restrict__ Sloc, const float* __restrict__ Kloc,
                        float* __restrict__ Sin, float* __restrict__ Kin) {
    int idx = blockIdx.x * 256 + threadIdx.x;   // 4096 = B*A
    int a = idx & 511, b = idx >> 9;
    int h = a >> 6;
    float r = tw[h * TTLEN + TTLEN - 2];
    float rL = r;
#pragma unroll
    for (int i = 0; i < 5; ++i) rL *= rL;       // r^32
    float cs = 0.f, ck = 0.f;
#pragma unroll
    for (int j = 0; j < NCH; ++j) {
        int o = (b * NCH + j) * 512 + a;
        Sin[o] = cs; Kin[o] = ck;
        cs = fmaf(rL, cs, Sloc[o]);
        ck += Kloc[o];
    }
}

// ------------- scan phase B: replay with true prefix, emit rwkv bf16, 4 ch/thread ----
__global__ void scanB(const ushort_t* __restrict__ kb, const ushort_t* __restrict__ vb,
                      const ushort_t* __restrict__ rb,
                      const float* __restrict__ tw, const float* __restrict__ alpha,
                      const float* __restrict__ beta,
                      const float* __restrict__ Sin, const float* __restrict__ Kin,
                      ushort_t* __restrict__ rwkv) {
    int b = blockIdx.x >> 6, j = blockIdx.x & 63;
    int a0 = threadIdx.x * 4;
    int h = a0 >> 6;
    float r = tw[h * TTLEN + TTLEN - 2];
    int t0 = j * CLEN;
    size_t base = ((size_t)(b * TTLEN + t0)) * 512 + a0;
    const float* al = alpha + h * TTLEN + t0;
    const float* bt = beta + h * TTLEN + t0;
    int o = (b * NCH + j) * 512 + a0;
    float4 sv = *(const float4*)(Sin + o);
    float4 kv = *(const float4*)(Kin + o);
    float s[4] = {sv.x, sv.y, sv.z, sv.w};
    float sk[4] = {kv.x, kv.y, kv.z, kv.w};
#pragma unroll 4
    for (int it = 0; it < CLEN; ++it) {
        uint2 kk = *(const uint2*)(kb + base + (size_t)it * 512);
        uint2 vv = *(const uint2*)(vb + base + (size_t)it * 512);
        uint2 rr = *(const uint2*)(rb + base + (size_t)it * 512);
        float kf[4] = {bf2f(kk.x & 0xffff), bf2f(kk.x >> 16),
                       bf2f(kk.y & 0xffff), bf2f(kk.y >> 16)};
        float vf[4] = {bf2f(vv.x & 0xffff), bf2f(vv.x >> 16),
                       bf2f(vv.y & 0xffff), bf2f(vv.y >> 16)};
        float rf[4] = {bf2f(rr.x & 0xffff), bf2f(rr.x >> 16),
                       bf2f(rr.y & 0xffff), bf2f(rr.y >> 16)};
        float av = al[it], btv = bt[it];
        unsigned short u[4];
#pragma unroll
        for (int c = 0; c < 4; ++c) {
            sk[c] += kf[c];
            s[c] = fmaf(r, s[c], av * kf[c] * vf[c]);
            u[c] = f2bf(rf[c] * btv * s[c] / sk[c]);
        }
        uint2 outw;
        outw.x = ((unsigned int)u[1] << 16) | u[0];
        outw.y = ((unsigned int)u[3] << 16) | u[2];
        *(uint2*)(rwkv + base + (size_t)it * 512) = outw;
    }
}

extern "C" void kernel_launch(void* const* d_in, const int* in_sizes, int n_in,
                              void* d_out, int out_size, void* d_ws, size_t ws_size,
                              hipStream_t stream) {
    const float* x   = (const float*)d_in[0];
    const float* tw  = (const float*)d_in[1];
    const float* ta  = (const float*)d_in[2];
    const float* tb  = (const float*)d_in[3];
    const float* tg  = (const float*)d_in[4];
    const float* tmk = (const float*)d_in[5];
    const float* tmv = (const float*)d_in[6];
    const float* tmr = (const float*)d_in[7];
    const float* Wk  = (const float*)d_in[8];
    const float* bk  = (const float*)d_in[9];
    const float* Wv  = (const float*)d_in[10];
    const float* bv  = (const float*)d_in[11];
    const float* Wr  = (const float*)d_in[12];
    const float* br  = (const float*)d_in[13];
    const float* Wo  = (const float*)d_in[14];
    const float* bo  = (const float*)d_in[15];

    char* ws = (char*)d_ws;
    ushort_t* Wall = (ushort_t*)(ws + 0);            // [1536][512] bf16 (Wk;Wv;Wr)
    ushort_t* Wob  = (ushort_t*)(ws + 1572864);      // [512][512] bf16
    ushort_t* xk   = (ushort_t*)(ws + 2097152);      // 16.78 MB each
    ushort_t* xv   = (ushort_t*)(ws + 18874368);
    ushort_t* xr   = (ushort_t*)(ws + 35651584);
    ushort_t* kb   = (ushort_t*)(ws + 52428800);
    ushort_t* vb   = (ushort_t*)(ws + 69206016);
    ushort_t* rb   = (ushort_t*)(ws + 85983232);
    ushort_t* rwkv = xk;                             // xk dead after gemm<0>
    float* Sloc = (float*)(ws + 102760448);          // 1 MB each
    float* Kloc = (float*)(ws + 103809024);
    float* Sin  = (float*)(ws + 104857600);
    float* Kin  = (float*)(ws + 105906176);

    convert4<<<1024, 256, 0, stream>>>(Wk, Wv, Wr, Wo, Wall, Wob);
    mix3<<<8192, 256, 0, stream>>>(x, tmk, tmv, tmr, xk, xv, xr);

    gemm_big<0><<<dim3(6, 128), 512, 0, stream>>>(xk, xv, xr, Wall, bk, bv, br,
                                                  kb, vb, rb, nullptr, nullptr);

    scanA<<<512, 128, 0, stream>>>(kb, vb, tw, ta, Sloc, Kloc);
    scanMid<<<16, 256, 0, stream>>>(tw, Sloc, Kloc, Sin, Kin);
    scanB<<<512, 128, 0, stream>>>(kb, vb, rb, tw, ta, tb, Sin, Kin, rwkv);

    gemm_big<1><<<dim3(2, 128), 512, 0, stream>>>(rwkv, nullptr, nullptr, Wob, bo, nullptr,
                                                  nullptr, nullptr, nullptr, nullptr,
                                                  (float*)d_out, tg);
}